// Round 9
// baseline (163.517 us; speedup 1.0000x reference)
//
#include <hip/hip_runtime.h>
#include <math.h>

#define B_      16
#define K_      200000
#define N_      40
#define TPB     256
#define CBX     128                          // chunks per batch
#define CHUNK   1564                         // even; 128*1564 = 200192 >= K_
#define NPI     4                            // pair-iters: ceil((CHUNK/2)/TPB)
#define NBLOCKS (CBX * B_)                   // 2048 (= 8 blocks/CU)
#define NE      (2 * N_)                     // 80 endpoints
#define NACC    7
#define PACC    8

// ws: [0, NBLOCKS*PACC*4) per-block partials (65,536 B). Nothing else.

typedef float v2f __attribute__((ext_vector_type(2)));
typedef float v4f __attribute__((ext_vector_type(4)));

// saddr-form asm loads: SGPR base + 32-bit VGPR byte offset, results pinned.
__device__ __forceinline__ v4f ld4s(const float* sbase, unsigned off) {
    v4f r;
    asm volatile("global_load_dwordx4 %0, %1, %2"
                 : "=v"(r) : "v"(off), "s"(sbase) : "memory");
    return r;
}
__device__ __forceinline__ v2f ld2s(const float* sbase, unsigned off) {
    v2f r;
    asm volatile("global_load_dwordx2 %0, %1, %2"
                 : "=v"(r) : "v"(off), "s"(sbase) : "memory");
    return r;
}
// counted vmem wait + scheduling fence (rule #18: fence mandatory after wait)
#define WAITV(N) do { asm volatile("s_waitcnt vmcnt(" #N ")" ::: "memory"); \
                      __builtin_amdgcn_sched_barrier(0); } while (0)
// LDS-only barrier for table build (never drains vmcnt -> prefetch survives)
#define LBAR()   do { asm volatile("s_waitcnt lgkmcnt(0)" ::: "memory"); \
                      __builtin_amdgcn_sched_barrier(0); \
                      __builtin_amdgcn_s_barrier(); \
                      __builtin_amdgcn_sched_barrier(0); } while (0)

// ---- both elements of a pair in ONE branch-free scheduling region ----
// Two independent dependency chains -> in-order SIMD fills one chain's
// trans/LDS latency stalls with the other's issue.
__device__ __forceinline__ void pair_accum(
    const float c0, const float c1,
    const v4f L, const v4f C4, const v4f P4, const v4f Q4, const v2f G,
    const float wt,                            // 1.0 pair valid, else 0.0
    const int base, const int end,
    const float* __restrict__ s_bp,
    const float4* __restrict__ s_tab,          // [0..79]=at, [80..160]=gap
    float& f0, float& f1, float& f2, float& f3,
    float& f4, float& f5, float& f6)
{
    const float EPS = 1.1920928955078125e-7f;  // FLT_EPSILON

    // fused match loop (one pass over s_bp for both elements)
    int pos0 = base, pos1 = base; bool eq0 = false, eq1 = false;
    for (int i = base; i < end; ++i) {           // block-uniform bounds
        const float v = s_bp[i];                 // broadcast read
        pos0 += (v <= c0) ? 1 : 0;  eq0 |= (v == c0);
        pos1 += (v <= c1) ? 1 : 0;  eq1 |= (v == c1);
    }
    const float4 sg0 = s_tab[eq0 ? (pos0 - 1) : (NE + pos0)];
    const float4 sg1 = s_tab[eq1 ? (pos1 - 1) : (NE + pos1)];

    auto chain = [&](const float c, const float4 sg,
                     const float pl, const float pr,
                     const float x0, const float x1,
                     const float p0, const float p1,
                     const float y0, const float y1,
                     const float lg) {
        const float tl = sg.x, tr = sg.y;
        const int conf_t = (int)sg.z;            // 0 when unmatched
        const float lt0 = (c - tl) * 256.0f;
        const float lt1 = (tr - c) * 256.0f;

        const float inter = fminf(pl, lt0) + fminf(pr, lt1);
        const float uni   = pl + pr + (lt0 + lt1) - inter;
        const float iou   = __fdividef(inter, fmaxf(uni, EPS));
        const int pconf_t = (iou < 0.5f) ? 0 : conf_t;

        const float posf = (conf_t > 0) ? wt : 0.0f;
        const float ppf  = (pconf_t > 0) ? wt : 0.0f;

        // GIoU (pos only)
        const float ac   = fmaxf(pl, lt0) + fmaxf(pr, lt1);
        const float giou = iou - __fdividef(ac - uni, fmaxf(ac, EPS));
        f0 += (1.0f - giou) * posf;

        // prop loc L1 (prop-pos only)
        const float prop_w = pl + pr;
        const float rw = __fdividef(1.0f, 0.5f * prop_w);
        const float plt0 = (lt0 - pl) * rw;
        const float plt1 = (lt1 - pr) * rw;
        f2 += (fabsf(p0 - plt0) + fabsf(p1 - plt1)) * ppf;

        // centerness BCE (pos only)
        const float cur0 = 0.5f * prop_w * p0 + pl;
        const float cur1 = 0.5f * prop_w * p1 + pr;
        const float inter2 = fminf(cur0, lt0) + fminf(cur1, lt1);
        const float uni2   = cur0 + cur1 + (lt0 + lt1) - inter2;
        const float iou2   = fmaxf(__fdividef(inter2, fmaxf(uni2, EPS)), 0.0f);
        const float bce = fmaxf(lg, 0.0f) - lg * iou2
                          + __logf(1.0f + __expf(-fabsf(lg)));
        f4 += bce * posf;

        // focal on conf (all elements; gated by wt)
        {
            const float xt = conf_t ? x1 : x0;
            const float xo = conf_t ? x0 : x1;
            const float pt = __fdividef(1.0f, 1.0f + __expf(xo - xt)) + 1e-6f;
            const float al = conf_t ? 0.75f : 0.25f;
            const float om = 1.0f - pt;
            f1 += -om * om * al * __logf(pt) * wt;
        }
        // focal on prop_conf (all elements; gated by wt)
        {
            const float xt = pconf_t ? y1 : y0;
            const float xo = pconf_t ? y0 : y1;
            const float pt = __fdividef(1.0f, 1.0f + __expf(xo - xt)) + 1e-6f;
            const float al = pconf_t ? 0.75f : 0.25f;
            const float om = 1.0f - pt;
            f3 += -om * om * al * __logf(pt) * wt;
        }

        f5 += posf;
        f6 += ppf;
    };
    chain(c0, sg0, L.x, L.y, C4.x, C4.y, P4.x, P4.y, Q4.x, Q4.y, G.x);
    chain(c1, sg1, L.z, L.w, C4.z, C4.w, P4.z, P4.w, Q4.z, Q4.w, G.y);
}

__global__ __launch_bounds__(TPB) void msl_main(
    const float* __restrict__ loc,     // (B,K,2)
    const float* __restrict__ conf,    // (B,K,2)
    const float* __restrict__ ploc,    // (B,K,2)
    const float* __restrict__ pconf,   // (B,K,2)
    const float* __restrict__ center,  // (B,K,1)
    const float* __restrict__ priors,  // (K,1)
    const float* __restrict__ targets, // (B,N,3)
    char* __restrict__ ws)
{
    __shared__ float  tl0[N_], tr0[N_], lb0[N_], ar0[N_];
    __shared__ float  stl[N_], str[N_], slb[N_];
    __shared__ float  s_ep[NE];
    __shared__ float  s_bp[NE];
    __shared__ float4 s_tab[2 * NE + 1];   // [0..79]=at, [80..160]=gap
    __shared__ int    s_cnt[4];
    __shared__ float  s_redf[TPB / 64][NACC];

    const int b  = blockIdx.y;
    const int cb = blockIdx.x;
    const int t  = threadIdx.x;
    const int kb = cb * CHUNK;
    const int kend = (kb + CHUNK < K_) ? kb + CHUNK : K_;   // even

    const int bK  = b * K_;
    const int bK2 = bK * 2;

    // ======== phase 1: targets -> LDS ========
    if (t < N_) {
        const float* tg = targets + (b * N_ + t) * 3;
        const float tl = tg[0], tr = tg[1];
        tl0[t] = tl; tr0[t] = tr; lb0[t] = tg[2];
        ar0[t] = (tr - tl) * 256.0f;
    }
    __builtin_amdgcn_sched_barrier(0);

    // ---- issue pairs 0 and 1 now (12 loads in flight across table build) ----
    v4f LA, CA, PA, QA;  v2f GA, RA;       // current pair
    v4f LB, CB, PB, QB;  v2f GB, RB;       // next pair
    #define ISSUE(Lx, Cx, Px, Qx, Gx, Rx, pidx) do {                      \
        const int p_  = (pidx);                                           \
        const int kk_ = kb + 2 * p_;                                      \
        const int kc_ = (kk_ < kend) ? kk_ : kb;   /* clamp: kb valid */  \
        const unsigned o4_ = (unsigned)(bK2 + kc_ * 2) * 4u;              \
        const unsigned oc_ = (unsigned)(bK + kc_) * 4u;                   \
        const unsigned op_ = (unsigned)kc_ * 4u;                          \
        Lx = ld4s(loc,  o4_);  Cx = ld4s(conf,  o4_);                     \
        Px = ld4s(ploc, o4_);  Qx = ld4s(pconf, o4_);                     \
        Gx = ld2s(center, oc_); Rx = ld2s(priors, op_);                   \
    } while (0)
    ISSUE(LA, CA, PA, QA, GA, RA, t);
    ISSUE(LB, CB, PB, QB, GB, RB, t + TPB);

    LBAR();

    // phase 2: stable rank-sort segments by area (tie: orig index) + ep build
    if (t < N_) {
        const float an = ar0[t];
        int r = 0;
        #pragma unroll
        for (int m = 0; m < N_; ++m) {
            const float am = ar0[m];
            r += (am < an) || (am == an && m < t);
        }
        stl[r] = tl0[t]; str[r] = tr0[t]; slb[r] = lb0[t];
    }
    if (t < NE) s_ep[t] = (t < N_) ? tl0[t] : tr0[t - N_];
    LBAR();

    // phase 3: rank-sort endpoints
    if (t < NE) {
        const float v = s_ep[t];
        int r = 0;
        #pragma unroll
        for (int m = 0; m < NE; ++m) {
            const float vm = s_ep[m];
            r += (vm < v) || (vm == v && m < t);
        }
        s_bp[r] = v;
    }
    LBAR();

    // phase 4: winner tables + range ballot
    if (t < 128) {
        const float v = (t < NE) ? s_bp[t] : INFINITY;
        const float cmin = priors[kb];              // uniform -> s_load (lgkm)
        const float cmax = priors[kend - 1];
        const unsigned long long mlo = __ballot(v < cmin);
        const unsigned long long mhi = __ballot(v <= cmax);
        const int wv = t >> 6;
        if ((t & 63) == 0) {
            s_cnt[wv]     = __popcll(mlo);
            s_cnt[2 + wv] = __popcll(mhi);
        }
    }
    if (t < NE) {                                    // point winners
        const float v = s_bp[t];
        int w = N_;
        for (int s = N_ - 1; s >= 0; --s)
            w = (stl[s] <= v && v <= str[s]) ? s : w;
        const bool ok = (w < N_);
        const int si = ok ? w : 0;
        s_tab[t] = ok ? make_float4(stl[si], str[si], slb[si], 1.0f)
                      : make_float4(0.f, 0.f, 0.f, 0.f);
    }
    if (t >= 128 && t < 128 + NE + 1) {              // gap winners
        const int g = t - 128;
        const float a  = g ? s_bp[g - 1] : -INFINITY;
        const float bb = (g < NE) ? s_bp[g] : INFINITY;
        int w = N_;
        for (int s = N_ - 1; s >= 0; --s)
            w = (stl[s] <= a && bb <= str[s]) ? s : w;
        const bool ok = (w < N_);
        const int si = ok ? w : 0;
        s_tab[NE + g] = ok ? make_float4(stl[si], str[si], slb[si], 1.0f)
                           : make_float4(0.f, 0.f, 0.f, 0.f);
    }
    LBAR();

    const int base = s_cnt[0] + s_cnt[1];
    const int end  = s_cnt[2] + s_cnt[3];

    // ======== compute: pair-ILP regions + 1-pair-ahead asm prefetch ========
    float f0 = 0.f, f1 = 0.f, f2 = 0.f, f3 = 0.f, f4 = 0.f, f5 = 0.f, f6 = 0.f;

    #pragma unroll
    for (int it = 0; it < NPI; ++it) {
        if (it < NPI - 1) WAITV(6);   // drain current pair; keep next in flight
        else              WAITV(0);
        const float wt =
            (kb + 2 * (t + it * TPB) < kend) ? 1.0f : 0.0f;
        pair_accum(RA.x, RA.y, LA, CA, PA, QA, GA, wt,
                   base, end, s_bp, s_tab, f0, f1, f2, f3, f4, f5, f6);
        __builtin_amdgcn_sched_barrier(0);
        v4f LC = {0,0,0,0}, CC = {0,0,0,0}, PC = {0,0,0,0}, QC = {0,0,0,0};
        v2f GC = {0,0}, RC = {0,0};
        if (it + 2 < NPI)                  // compile-time uniform branch
            ISSUE(LC, CC, PC, QC, GC, RC, t + (it + 2) * TPB);
        // rotate register sets (SSA renaming under full unroll)
        LA = LB; CA = CB; PA = PB; QA = QB; GA = GB; RA = RB;
        LB = LC; CB = CC; PB = PC; QB = QC; GB = GC; RB = RC;
    }
    #undef ISSUE

    // ---- block reduction (f32 wave tree, f64 cross-wave) -> partials ----
    {
        float vals[NACC] = {f0, f1, f2, f3, f4, f5, f6};
        const int wave = t >> 6, lane = t & 63;
        #pragma unroll
        for (int q = 0; q < NACC; ++q) {
            float v = vals[q];
            #pragma unroll
            for (int off = 32; off > 0; off >>= 1)
                v += __shfl_down(v, off, 64);
            if (lane == 0) s_redf[wave][q] = v;
        }
    }
    __syncthreads();
    if (t == 0) {
        float* partials = (float*)ws;
        const int bid = b * CBX + cb;
        #pragma unroll
        for (int q = 0; q < NACC; ++q) {
            double s = 0.0;
            #pragma unroll
            for (int w2 = 0; w2 < TPB / 64; ++w2) s += (double)s_redf[w2][q];
            partials[bid * PACC + q] = (float)s;
        }
    }
}

__global__ __launch_bounds__(TPB) void msl_final(
    const float* __restrict__ partials, float* __restrict__ out)
{
    __shared__ double s_red[TPB / 64][NACC];
    double acc[NACC] = {0, 0, 0, 0, 0, 0, 0};
    for (int i = threadIdx.x; i < NBLOCKS; i += TPB) {
        #pragma unroll
        for (int q = 0; q < NACC; ++q)
            acc[q] += (double)partials[i * PACC + q];
    }
    const int wave = threadIdx.x >> 6, lane = threadIdx.x & 63;
    #pragma unroll
    for (int q = 0; q < NACC; ++q) {
        double v = acc[q];
        #pragma unroll
        for (int off = 32; off > 0; off >>= 1)
            v += __shfl_down(v, off, 64);
        if (lane == 0) s_red[wave][q] = v;
    }
    __syncthreads();
    if (threadIdx.x == 0) {
        double s[NACC];
        #pragma unroll
        for (int q = 0; q < NACC; ++q) {
            double v = 0.0;
            #pragma unroll
            for (int w = 0; w < TPB / 64; ++w) v += s_red[w][q];
            s[q] = v;
        }
        const double Np = fmax(s[5], 1.0);
        const double PN = fmax(s[6], 1.0);
        out[0] = (float)(s[0] / Np);
        out[1] = (float)(s[1] / Np);
        out[2] = (float)(s[2] / PN);
        out[3] = (float)(s[3] / PN);
        out[4] = (float)(s[4] / Np);
    }
}

extern "C" void kernel_launch(void* const* d_in, const int* in_sizes, int n_in,
                              void* d_out, int out_size, void* d_ws, size_t ws_size,
                              hipStream_t stream) {
    const float* loc     = (const float*)d_in[0];
    const float* conf    = (const float*)d_in[1];
    const float* ploc    = (const float*)d_in[2];
    const float* pconf   = (const float*)d_in[3];
    const float* center  = (const float*)d_in[4];
    const float* priors  = (const float*)d_in[5];
    const float* targets = (const float*)d_in[6];
    char* ws = (char*)d_ws;   // uses 65,536 bytes (partials only)

    dim3 grid(CBX, B_);
    msl_main<<<grid, TPB, 0, stream>>>(loc, conf, ploc, pconf, center, priors,
                                       targets, ws);
    msl_final<<<1, TPB, 0, stream>>>((const float*)ws, (float*)d_out);
}

// Round 10
// 157.541 us; speedup vs baseline: 1.0379x; 1.0379x over previous
//
#include <hip/hip_runtime.h>
#include <math.h>

#define B_      16
#define K_      200000
#define N_      40
#define TPB     256
#define CBX     196                          // chunks per batch
#define CHUNK   1024                         // 196*1024 = 200704 >= K_
#define NITER   4                            // CHUNK / TPB exactly
#define NBLOCKS (CBX * B_)                   // 3136 (12.25 blocks/CU, oversub)
#define NE      (2 * N_)                     // 80 endpoints
#define NACC    7
#define PACC    8

// ws: [0, NBLOCKS*PACC*4) per-block partials (100,352 B). Nothing else.

typedef float v2f __attribute__((ext_vector_type(2)));

// saddr-form asm loads: SGPR-pair base + 32-bit VGPR byte offset.
// Issue order = program order; results pinned; minimal VGPR addressing cost.
__device__ __forceinline__ v2f ld2s(const float* sbase, unsigned off) {
    v2f r;
    asm volatile("global_load_dwordx2 %0, %1, %2"
                 : "=v"(r) : "v"(off), "s"(sbase) : "memory");
    return r;
}
__device__ __forceinline__ float ld1s(const float* sbase, unsigned off) {
    float r;
    asm volatile("global_load_dword %0, %1, %2"
                 : "=v"(r) : "v"(off), "s"(sbase) : "memory");
    return r;
}
// counted vmem wait + scheduling fence (rule #18)
#define WAITV(N) do { asm volatile("s_waitcnt vmcnt(" #N ")" ::: "memory"); \
                      __builtin_amdgcn_sched_barrier(0); } while (0)
// LDS-only barrier for table build (never drains vmcnt -> prologue prefetch
// stays in flight across it)
#define LBAR()   do { asm volatile("s_waitcnt lgkmcnt(0)" ::: "memory"); \
                      __builtin_amdgcn_sched_barrier(0); \
                      __builtin_amdgcn_s_barrier(); \
                      __builtin_amdgcn_sched_barrier(0); } while (0)

__device__ __forceinline__ void elem_accum(
    const float c, const float pl, const float pr,
    const float x0, const float x1,
    const float p0, const float p1,
    const float y0, const float y1,
    const float lg,
    const int base, const int end,
    const float* __restrict__ s_bp,
    const float4* __restrict__ s_tab,          // [0..79]=at, [80..160]=gap
    float& f0, float& f1, float& f2, float& f3,
    float& f4, float& f5, float& f6)
{
    const float EPS = 1.1920928955078125e-7f;  // FLT_EPSILON

    // ---- match: pos = #bp <= c; in-range bp are contiguous [base,end) ----
    int pos = base; bool eq = false;
    for (int i = base; i < end; ++i) {           // block-uniform bounds
        const float v = s_bp[i];                 // broadcast read
        pos += (v <= c) ? 1 : 0;
        eq  |= (v == c);
    }
    const int idx = eq ? (pos - 1) : (NE + pos);
    const float4 sg = s_tab[idx];

    const float tl = sg.x, tr = sg.y;
    const int conf_t = (int)sg.z;                // 0 when unmatched
    const float lt0 = (c - tl) * 256.0f;
    const float lt1 = (tr - c) * 256.0f;

    // ---- iou(loc, loc_t) ----
    const float inter = fminf(pl, lt0) + fminf(pr, lt1);
    const float uni   = pl + pr + (lt0 + lt1) - inter;
    const float iou   = __fdividef(inter, fmaxf(uni, EPS));
    const int pconf_t = (iou < 0.5f) ? 0 : conf_t;

    const float posf = (conf_t > 0) ? 1.0f : 0.0f;
    const float ppf  = (pconf_t > 0) ? 1.0f : 0.0f;

    // GIoU (pos only)
    const float ac   = fmaxf(pl, lt0) + fmaxf(pr, lt1);
    const float giou = iou - __fdividef(ac - uni, fmaxf(ac, EPS));
    f0 += (1.0f - giou) * posf;

    // prop loc L1 (prop-pos only)
    const float prop_w = pl + pr;
    const float rw = __fdividef(1.0f, 0.5f * prop_w);
    const float plt0 = (lt0 - pl) * rw;
    const float plt1 = (lt1 - pr) * rw;
    f2 += (fabsf(p0 - plt0) + fabsf(p1 - plt1)) * ppf;

    // centerness BCE (pos only)
    const float cur0 = 0.5f * prop_w * p0 + pl;
    const float cur1 = 0.5f * prop_w * p1 + pr;
    const float inter2 = fminf(cur0, lt0) + fminf(cur1, lt1);
    const float uni2   = cur0 + cur1 + (lt0 + lt1) - inter2;
    const float iou2   = fmaxf(__fdividef(inter2, fmaxf(uni2, EPS)), 0.0f);
    const float bce = fmaxf(lg, 0.0f) - lg * iou2
                      + __logf(1.0f + __expf(-fabsf(lg)));
    f4 += bce * posf;

    // focal on conf (all elements)
    {
        const float xt = conf_t ? x1 : x0;
        const float xo = conf_t ? x0 : x1;
        const float pt = __fdividef(1.0f, 1.0f + __expf(xo - xt)) + 1e-6f;
        const float al = conf_t ? 0.75f : 0.25f;
        const float om = 1.0f - pt;
        f1 += -om * om * al * __logf(pt);
    }
    // focal on prop_conf (all elements)
    {
        const float xt = pconf_t ? y1 : y0;
        const float xo = pconf_t ? y0 : y1;
        const float pt = __fdividef(1.0f, 1.0f + __expf(xo - xt)) + 1e-6f;
        const float al = pconf_t ? 0.75f : 0.25f;
        const float om = 1.0f - pt;
        f3 += -om * om * al * __logf(pt);
    }

    f5 += posf;
    f6 += ppf;
}

__global__ __launch_bounds__(TPB) void msl_main(
    const float* __restrict__ loc,     // (B,K,2)
    const float* __restrict__ conf,    // (B,K,2)
    const float* __restrict__ ploc,    // (B,K,2)
    const float* __restrict__ pconf,   // (B,K,2)
    const float* __restrict__ center,  // (B,K,1)
    const float* __restrict__ priors,  // (K,1)
    const float* __restrict__ targets, // (B,N,3)
    char* __restrict__ ws)
{
    __shared__ float  tl0[N_], tr0[N_], lb0[N_], ar0[N_];
    __shared__ float  stl[N_], str[N_], slb[N_];
    __shared__ float  s_ep[NE];
    __shared__ float  s_bp[NE];
    __shared__ float4 s_tab[2 * NE + 1];   // [0..79]=at, [80..160]=gap
    __shared__ int    s_cnt[4];
    __shared__ float  s_redf[TPB / 64][NACC];

    const int b  = blockIdx.y;
    const int cb = blockIdx.x;
    const int t  = threadIdx.x;
    const int kb = cb * CHUNK;
    const int kend = (kb + CHUNK < K_) ? kb + CHUNK : K_;

    const int bK  = b * K_;
    const int bK2 = bK * 2;

    // ======== phase 1: targets -> LDS ========
    if (t < N_) {
        const float* tg = targets + (b * N_ + t) * 3;
        const float tl = tg[0], tr = tg[1];
        tl0[t] = tl; tr0[t] = tr; lb0[t] = tg[2];
        ar0[t] = (tr - tl) * 256.0f;
    }
    __builtin_amdgcn_sched_barrier(0);

    // ---- issue items 0 AND 1 now (12 loads in flight across the whole
    //      table build -- LBAR never drains vmcnt) ----
    int  k  = kb + t;
    bool vc = (k < kend);
    v2f lA, cA, pA, qA; float gA, rA;      // current item
    v2f lB, cB, pB, qB; float gB, rB;      // next item
    {
        const int k0 = vc ? k : (kend - 1);
        const unsigned o4 = (unsigned)(bK2 + k0 * 2) * 4u;
        const unsigned oc = (unsigned)(bK + k0) * 4u;
        const unsigned op = (unsigned)k0 * 4u;
        lA = ld2s(loc, o4);  cA = ld2s(conf, o4);
        pA = ld2s(ploc, o4); qA = ld2s(pconf, o4);
        gA = ld1s(center, oc); rA = ld1s(priors, op);
    }
    {
        const int k1 = k + TPB;
        const int kc = (k1 < kend) ? k1 : (kend - 1);
        const unsigned o4 = (unsigned)(bK2 + kc * 2) * 4u;
        const unsigned oc = (unsigned)(bK + kc) * 4u;
        const unsigned op = (unsigned)kc * 4u;
        lB = ld2s(loc, o4);  cB = ld2s(conf, o4);
        pB = ld2s(ploc, o4); qB = ld2s(pconf, o4);
        gB = ld1s(center, oc); rB = ld1s(priors, op);
    }

    LBAR();

    // phase 2: stable rank-sort segments by area (tie: orig index) + ep build
    if (t < N_) {
        const float an = ar0[t];
        int r = 0;
        #pragma unroll
        for (int m = 0; m < N_; ++m) {
            const float am = ar0[m];
            r += (am < an) || (am == an && m < t);
        }
        stl[r] = tl0[t]; str[r] = tr0[t]; slb[r] = lb0[t];
    }
    if (t < NE) s_ep[t] = (t < N_) ? tl0[t] : tr0[t - N_];
    LBAR();

    // phase 3: rank-sort endpoints
    if (t < NE) {
        const float v = s_ep[t];
        int r = 0;
        #pragma unroll
        for (int m = 0; m < NE; ++m) {
            const float vm = s_ep[m];
            r += (vm < v) || (vm == v && m < t);
        }
        s_bp[r] = v;
    }
    LBAR();

    // phase 4: winner tables + range ballot (one phase, one barrier)
    if (t < 128) {
        const float v = (t < NE) ? s_bp[t] : INFINITY;
        const float cmin = priors[kb];              // uniform -> s_load (lgkm)
        const float cmax = priors[kend - 1];
        const unsigned long long mlo = __ballot(v < cmin);
        const unsigned long long mhi = __ballot(v <= cmax);
        const int wv = t >> 6;
        if ((t & 63) == 0) {
            s_cnt[wv]     = __popcll(mlo);
            s_cnt[2 + wv] = __popcll(mhi);
        }
    }
    if (t < NE) {                                    // point winners
        const float v = s_bp[t];
        int w = N_;
        for (int s = N_ - 1; s >= 0; --s)
            w = (stl[s] <= v && v <= str[s]) ? s : w;
        const bool ok = (w < N_);
        const int si = ok ? w : 0;
        s_tab[t] = ok ? make_float4(stl[si], str[si], slb[si], 1.0f)
                      : make_float4(0.f, 0.f, 0.f, 0.f);
    }
    if (t >= 128 && t < 128 + NE + 1) {              // gap winners
        const int g = t - 128;
        const float a  = g ? s_bp[g - 1] : -INFINITY;
        const float bb = (g < NE) ? s_bp[g] : INFINITY;
        int w = N_;
        for (int s = N_ - 1; s >= 0; --s)
            w = (stl[s] <= a && bb <= str[s]) ? s : w;
        const bool ok = (w < N_);
        const int si = ok ? w : 0;
        s_tab[NE + g] = ok ? make_float4(stl[si], str[si], slb[si], 1.0f)
                           : make_float4(0.f, 0.f, 0.f, 0.f);
    }
    LBAR();

    const int base = s_cnt[0] + s_cnt[1];
    const int end  = s_cnt[2] + s_cnt[3];

    // ======== compute: asm-forced 2-deep prefetch, counted vmcnt ========
    float f0 = 0.f, f1 = 0.f, f2 = 0.f, f3 = 0.f, f4 = 0.f, f5 = 0.f, f6 = 0.f;

    #pragma unroll
    for (int it = 0; it < NITER; ++it) {
        v2f lC = {0.f, 0.f}, cC = {0.f, 0.f}, pC = {0.f, 0.f}, qC = {0.f, 0.f};
        float gC = 0.f, rC = 0.f;
        if (it + 2 < NITER) {                 // compile-time uniform branch
            const int kn2 = k + 2 * TPB;
            const int knc = (kn2 < kend) ? kn2 : (kend - 1);   // clamp: no
            const unsigned o4 = (unsigned)(bK2 + knc * 2) * 4u;// divergent issue
            const unsigned oc = (unsigned)(bK + knc) * 4u;
            const unsigned op = (unsigned)knc * 4u;
            lC = ld2s(loc, o4);  cC = ld2s(conf, o4);
            pC = ld2s(ploc, o4); qC = ld2s(pconf, o4);
            gC = ld1s(center, oc); rC = ld1s(priors, op);
            WAITV(12);   // drain current's 6; keep 2 items (12 loads) in flight
        } else if (it + 2 == NITER) {
            WAITV(6);    // drain current's 6; keep last item's 6 in flight
        } else {
            WAITV(0);    // final iteration: drain everything
        }
        if (vc)
            elem_accum(rA, lA.x, lA.y, cA.x, cA.y,
                       pA.x, pA.y, qA.x, qA.y, gA,
                       base, end, s_bp, s_tab,
                       f0, f1, f2, f3, f4, f5, f6);
        // rotate register sets (pure SSA renaming under full unroll)
        lA = lB; cA = cB; pA = pB; qA = qB; gA = gB; rA = rB;
        lB = lC; cB = cC; pB = pC; qB = qC; gB = gC; rB = rC;
        k += TPB; vc = (k < kend);
    }

    // ---- block reduction (f32 wave tree, f64 cross-wave) -> partials ----
    {
        float vals[NACC] = {f0, f1, f2, f3, f4, f5, f6};
        const int wave = t >> 6, lane = t & 63;
        #pragma unroll
        for (int q = 0; q < NACC; ++q) {
            float v = vals[q];
            #pragma unroll
            for (int off = 32; off > 0; off >>= 1)
                v += __shfl_down(v, off, 64);
            if (lane == 0) s_redf[wave][q] = v;
        }
    }
    __syncthreads();
    if (t == 0) {
        float* partials = (float*)ws;
        const int bid = b * CBX + cb;
        #pragma unroll
        for (int q = 0; q < NACC; ++q) {
            double s = 0.0;
            #pragma unroll
            for (int w2 = 0; w2 < TPB / 64; ++w2) s += (double)s_redf[w2][q];
            partials[bid * PACC + q] = (float)s;
        }
    }
}

__global__ __launch_bounds__(TPB) void msl_final(
    const float* __restrict__ partials, float* __restrict__ out)
{
    __shared__ double s_red[TPB / 64][NACC];
    double acc[NACC] = {0, 0, 0, 0, 0, 0, 0};
    for (int i = threadIdx.x; i < NBLOCKS; i += TPB) {
        #pragma unroll
        for (int q = 0; q < NACC; ++q)
            acc[q] += (double)partials[i * PACC + q];
    }
    const int wave = threadIdx.x >> 6, lane = threadIdx.x & 63;
    #pragma unroll
    for (int q = 0; q < NACC; ++q) {
        double v = acc[q];
        #pragma unroll
        for (int off = 32; off > 0; off >>= 1)
            v += __shfl_down(v, off, 64);
        if (lane == 0) s_red[wave][q] = v;
    }
    __syncthreads();
    if (threadIdx.x == 0) {
        double s[NACC];
        #pragma unroll
        for (int q = 0; q < NACC; ++q) {
            double v = 0.0;
            #pragma unroll
            for (int w = 0; w < TPB / 64; ++w) v += s_red[w][q];
            s[q] = v;
        }
        const double Np = fmax(s[5], 1.0);
        const double PN = fmax(s[6], 1.0);
        out[0] = (float)(s[0] / Np);
        out[1] = (float)(s[1] / Np);
        out[2] = (float)(s[2] / PN);
        out[3] = (float)(s[3] / PN);
        out[4] = (float)(s[4] / Np);
    }
}

extern "C" void kernel_launch(void* const* d_in, const int* in_sizes, int n_in,
                              void* d_out, int out_size, void* d_ws, size_t ws_size,
                              hipStream_t stream) {
    const float* loc     = (const float*)d_in[0];
    const float* conf    = (const float*)d_in[1];
    const float* ploc    = (const float*)d_in[2];
    const float* pconf   = (const float*)d_in[3];
    const float* center  = (const float*)d_in[4];
    const float* priors  = (const float*)d_in[5];
    const float* targets = (const float*)d_in[6];
    char* ws = (char*)d_ws;   // uses 100,352 bytes (partials only)

    dim3 grid(CBX, B_);
    msl_main<<<grid, TPB, 0, stream>>>(loc, conf, ploc, pconf, center, priors,
                                       targets, ws);
    msl_final<<<1, TPB, 0, stream>>>((const float*)ws, (float*)d_out);
}

// Round 11
// 154.273 us; speedup vs baseline: 1.0599x; 1.0212x over previous
//
#include <hip/hip_runtime.h>
#include <math.h>

#define B_      16
#define K_      200000
#define N_      40
#define TPB     256
#define CBX     112                          // chunks per batch
#define CHUNK   1792                         // = 7*256 exactly; 112*1792 >= K_
#define NITER   7                            // CHUNK / TPB, zero-waste iters
#define NBLOCKS (CBX * B_)                   // 1792 (= 7 blocks/CU exactly)
#define NE      (2 * N_)                     // 80 endpoints
#define NACC    7
#define PACC    8

// ws: [0, NBLOCKS*PACC*4) per-block partials (57,344 B). Nothing else.

typedef float v2f __attribute__((ext_vector_type(2)));

// saddr-form asm loads: SGPR-pair base + 32-bit VGPR byte offset.
// Issue order = program order; results pinned; minimal VGPR addressing cost.
__device__ __forceinline__ v2f ld2s(const float* sbase, unsigned off) {
    v2f r;
    asm volatile("global_load_dwordx2 %0, %1, %2"
                 : "=v"(r) : "v"(off), "s"(sbase) : "memory");
    return r;
}
__device__ __forceinline__ float ld1s(const float* sbase, unsigned off) {
    float r;
    asm volatile("global_load_dword %0, %1, %2"
                 : "=v"(r) : "v"(off), "s"(sbase) : "memory");
    return r;
}
// counted vmem wait + scheduling fence (rule #18)
#define WAITV(N) do { asm volatile("s_waitcnt vmcnt(" #N ")" ::: "memory"); \
                      __builtin_amdgcn_sched_barrier(0); } while (0)
// LDS-only barrier for table build (never drains vmcnt -> prologue prefetch
// stays in flight across it)
#define LBAR()   do { asm volatile("s_waitcnt lgkmcnt(0)" ::: "memory"); \
                      __builtin_amdgcn_sched_barrier(0); \
                      __builtin_amdgcn_s_barrier(); \
                      __builtin_amdgcn_sched_barrier(0); } while (0)

__device__ __forceinline__ void elem_accum(
    const float c, const float pl, const float pr,
    const float x0, const float x1,
    const float p0, const float p1,
    const float y0, const float y1,
    const float lg,
    const int base, const int end,
    const float* __restrict__ s_bp,
    const float4* __restrict__ s_tab,          // [0..79]=at, [80..160]=gap
    float& f0, float& f1, float& f2, float& f3,
    float& f4, float& f5, float& f6)
{
    const float EPS = 1.1920928955078125e-7f;  // FLT_EPSILON

    // ---- match: pos = #bp <= c; in-range bp are contiguous [base,end) ----
    int pos = base; bool eq = false;
    for (int i = base; i < end; ++i) {           // block-uniform bounds
        const float v = s_bp[i];                 // broadcast read
        pos += (v <= c) ? 1 : 0;
        eq  |= (v == c);
    }
    const int idx = eq ? (pos - 1) : (NE + pos);
    const float4 sg = s_tab[idx];

    const float tl = sg.x, tr = sg.y;
    const int conf_t = (int)sg.z;                // 0 when unmatched
    const float lt0 = (c - tl) * 256.0f;
    const float lt1 = (tr - c) * 256.0f;

    // ---- iou(loc, loc_t) ----
    const float inter = fminf(pl, lt0) + fminf(pr, lt1);
    const float uni   = pl + pr + (lt0 + lt1) - inter;
    const float iou   = __fdividef(inter, fmaxf(uni, EPS));
    const int pconf_t = (iou < 0.5f) ? 0 : conf_t;

    const float posf = (conf_t > 0) ? 1.0f : 0.0f;
    const float ppf  = (pconf_t > 0) ? 1.0f : 0.0f;

    // GIoU (pos only)
    const float ac   = fmaxf(pl, lt0) + fmaxf(pr, lt1);
    const float giou = iou - __fdividef(ac - uni, fmaxf(ac, EPS));
    f0 += (1.0f - giou) * posf;

    // prop loc L1 (prop-pos only)
    const float prop_w = pl + pr;
    const float rw = __fdividef(1.0f, 0.5f * prop_w);
    const float plt0 = (lt0 - pl) * rw;
    const float plt1 = (lt1 - pr) * rw;
    f2 += (fabsf(p0 - plt0) + fabsf(p1 - plt1)) * ppf;

    // centerness BCE (pos only)
    const float cur0 = 0.5f * prop_w * p0 + pl;
    const float cur1 = 0.5f * prop_w * p1 + pr;
    const float inter2 = fminf(cur0, lt0) + fminf(cur1, lt1);
    const float uni2   = cur0 + cur1 + (lt0 + lt1) - inter2;
    const float iou2   = fmaxf(__fdividef(inter2, fmaxf(uni2, EPS)), 0.0f);
    const float bce = fmaxf(lg, 0.0f) - lg * iou2
                      + __logf(1.0f + __expf(-fabsf(lg)));
    f4 += bce * posf;

    // focal on conf (all elements)
    {
        const float xt = conf_t ? x1 : x0;
        const float xo = conf_t ? x0 : x1;
        const float pt = __fdividef(1.0f, 1.0f + __expf(xo - xt)) + 1e-6f;
        const float al = conf_t ? 0.75f : 0.25f;
        const float om = 1.0f - pt;
        f1 += -om * om * al * __logf(pt);
    }
    // focal on prop_conf (all elements)
    {
        const float xt = pconf_t ? y1 : y0;
        const float xo = pconf_t ? y0 : y1;
        const float pt = __fdividef(1.0f, 1.0f + __expf(xo - xt)) + 1e-6f;
        const float al = pconf_t ? 0.75f : 0.25f;
        const float om = 1.0f - pt;
        f3 += -om * om * al * __logf(pt);
    }

    f5 += posf;
    f6 += ppf;
}

__global__ __launch_bounds__(TPB) void msl_main(
    const float* __restrict__ loc,     // (B,K,2)
    const float* __restrict__ conf,    // (B,K,2)
    const float* __restrict__ ploc,    // (B,K,2)
    const float* __restrict__ pconf,   // (B,K,2)
    const float* __restrict__ center,  // (B,K,1)
    const float* __restrict__ priors,  // (K,1)
    const float* __restrict__ targets, // (B,N,3)
    char* __restrict__ ws)
{
    __shared__ float  tl0[N_], tr0[N_], lb0[N_], ar0[N_];
    __shared__ float  stl[N_], str[N_], slb[N_];
    __shared__ float  s_ep[NE];
    __shared__ float  s_bp[NE];
    __shared__ float4 s_tab[2 * NE + 1];   // [0..79]=at, [80..160]=gap
    __shared__ int    s_cnt[4];
    __shared__ float  s_redf[TPB / 64][NACC];

    const int b  = blockIdx.y;
    const int cb = blockIdx.x;
    const int t  = threadIdx.x;
    const int kb = cb * CHUNK;
    const int kend = (kb + CHUNK < K_) ? kb + CHUNK : K_;

    const int bK  = b * K_;
    const int bK2 = bK * 2;

    // ======== phase 1: targets -> LDS ========
    if (t < N_) {
        const float* tg = targets + (b * N_ + t) * 3;
        const float tl = tg[0], tr = tg[1];
        tl0[t] = tl; tr0[t] = tr; lb0[t] = tg[2];
        ar0[t] = (tr - tl) * 256.0f;
    }
    __builtin_amdgcn_sched_barrier(0);

    // ---- issue items 0 AND 1 now (12 loads in flight across the whole
    //      table build -- LBAR never drains vmcnt) ----
    int  k  = kb + t;
    bool vc = (k < kend);
    v2f lA, cA, pA, qA; float gA, rA;      // current item
    v2f lB, cB, pB, qB; float gB, rB;      // next item
    {
        const int k0 = vc ? k : (kend - 1);
        const unsigned o4 = (unsigned)(bK2 + k0 * 2) * 4u;
        const unsigned oc = (unsigned)(bK + k0) * 4u;
        const unsigned op = (unsigned)k0 * 4u;
        lA = ld2s(loc, o4);  cA = ld2s(conf, o4);
        pA = ld2s(ploc, o4); qA = ld2s(pconf, o4);
        gA = ld1s(center, oc); rA = ld1s(priors, op);
    }
    {
        const int k1 = k + TPB;
        const int kc = (k1 < kend) ? k1 : (kend - 1);
        const unsigned o4 = (unsigned)(bK2 + kc * 2) * 4u;
        const unsigned oc = (unsigned)(bK + kc) * 4u;
        const unsigned op = (unsigned)kc * 4u;
        lB = ld2s(loc, o4);  cB = ld2s(conf, o4);
        pB = ld2s(ploc, o4); qB = ld2s(pconf, o4);
        gB = ld1s(center, oc); rB = ld1s(priors, op);
    }

    LBAR();

    // phase 2: stable rank-sort segments by area (tie: orig index) + ep build
    if (t < N_) {
        const float an = ar0[t];
        int r = 0;
        #pragma unroll
        for (int m = 0; m < N_; ++m) {
            const float am = ar0[m];
            r += (am < an) || (am == an && m < t);
        }
        stl[r] = tl0[t]; str[r] = tr0[t]; slb[r] = lb0[t];
    }
    if (t < NE) s_ep[t] = (t < N_) ? tl0[t] : tr0[t - N_];
    LBAR();

    // phase 3: rank-sort endpoints
    if (t < NE) {
        const float v = s_ep[t];
        int r = 0;
        #pragma unroll
        for (int m = 0; m < NE; ++m) {
            const float vm = s_ep[m];
            r += (vm < v) || (vm == v && m < t);
        }
        s_bp[r] = v;
    }
    LBAR();

    // phase 4: winner tables + range ballot (one phase, one barrier)
    if (t < 128) {
        const float v = (t < NE) ? s_bp[t] : INFINITY;
        const float cmin = priors[kb];              // uniform -> s_load (lgkm)
        const float cmax = priors[kend - 1];
        const unsigned long long mlo = __ballot(v < cmin);
        const unsigned long long mhi = __ballot(v <= cmax);
        const int wv = t >> 6;
        if ((t & 63) == 0) {
            s_cnt[wv]     = __popcll(mlo);
            s_cnt[2 + wv] = __popcll(mhi);
        }
    }
    if (t < NE) {                                    // point winners
        const float v = s_bp[t];
        int w = N_;
        for (int s = N_ - 1; s >= 0; --s)
            w = (stl[s] <= v && v <= str[s]) ? s : w;
        const bool ok = (w < N_);
        const int si = ok ? w : 0;
        s_tab[t] = ok ? make_float4(stl[si], str[si], slb[si], 1.0f)
                      : make_float4(0.f, 0.f, 0.f, 0.f);
    }
    if (t >= 128 && t < 128 + NE + 1) {              // gap winners
        const int g = t - 128;
        const float a  = g ? s_bp[g - 1] : -INFINITY;
        const float bb = (g < NE) ? s_bp[g] : INFINITY;
        int w = N_;
        for (int s = N_ - 1; s >= 0; --s)
            w = (stl[s] <= a && bb <= str[s]) ? s : w;
        const bool ok = (w < N_);
        const int si = ok ? w : 0;
        s_tab[NE + g] = ok ? make_float4(stl[si], str[si], slb[si], 1.0f)
                           : make_float4(0.f, 0.f, 0.f, 0.f);
    }
    LBAR();

    const int base = s_cnt[0] + s_cnt[1];
    const int end  = s_cnt[2] + s_cnt[3];

    // ======== compute: asm-forced 2-deep prefetch, counted vmcnt ========
    float f0 = 0.f, f1 = 0.f, f2 = 0.f, f3 = 0.f, f4 = 0.f, f5 = 0.f, f6 = 0.f;

    #pragma unroll
    for (int it = 0; it < NITER; ++it) {
        v2f lC = {0.f, 0.f}, cC = {0.f, 0.f}, pC = {0.f, 0.f}, qC = {0.f, 0.f};
        float gC = 0.f, rC = 0.f;
        if (it + 2 < NITER) {                 // compile-time uniform branch
            const int kn2 = k + 2 * TPB;
            const int knc = (kn2 < kend) ? kn2 : (kend - 1);   // clamp: no
            const unsigned o4 = (unsigned)(bK2 + knc * 2) * 4u;// divergent issue
            const unsigned oc = (unsigned)(bK + knc) * 4u;
            const unsigned op = (unsigned)knc * 4u;
            lC = ld2s(loc, o4);  cC = ld2s(conf, o4);
            pC = ld2s(ploc, o4); qC = ld2s(pconf, o4);
            gC = ld1s(center, oc); rC = ld1s(priors, op);
            WAITV(12);   // drain current's 6; keep 2 items (12 loads) in flight
        } else if (it + 2 == NITER) {
            WAITV(6);    // drain current's 6; keep last item's 6 in flight
        } else {
            WAITV(0);    // final iteration: drain everything
        }
        if (vc)
            elem_accum(rA, lA.x, lA.y, cA.x, cA.y,
                       pA.x, pA.y, qA.x, qA.y, gA,
                       base, end, s_bp, s_tab,
                       f0, f1, f2, f3, f4, f5, f6);
        // rotate register sets (pure SSA renaming under full unroll)
        lA = lB; cA = cB; pA = pB; qA = qB; gA = gB; rA = rB;
        lB = lC; cB = cC; pB = pC; qB = qC; gB = gC; rB = rC;
        k += TPB; vc = (k < kend);
    }

    // ---- block reduction (f32 wave tree, f64 cross-wave) -> partials ----
    {
        float vals[NACC] = {f0, f1, f2, f3, f4, f5, f6};
        const int wave = t >> 6, lane = t & 63;
        #pragma unroll
        for (int q = 0; q < NACC; ++q) {
            float v = vals[q];
            #pragma unroll
            for (int off = 32; off > 0; off >>= 1)
                v += __shfl_down(v, off, 64);
            if (lane == 0) s_redf[wave][q] = v;
        }
    }
    __syncthreads();
    if (t == 0) {
        float* partials = (float*)ws;
        const int bid = b * CBX + cb;
        #pragma unroll
        for (int q = 0; q < NACC; ++q) {
            double s = 0.0;
            #pragma unroll
            for (int w2 = 0; w2 < TPB / 64; ++w2) s += (double)s_redf[w2][q];
            partials[bid * PACC + q] = (float)s;
        }
    }
}

__global__ __launch_bounds__(TPB) void msl_final(
    const float* __restrict__ partials, float* __restrict__ out)
{
    __shared__ double s_red[TPB / 64][NACC];
    double acc[NACC] = {0, 0, 0, 0, 0, 0, 0};
    for (int i = threadIdx.x; i < NBLOCKS; i += TPB) {
        #pragma unroll
        for (int q = 0; q < NACC; ++q)
            acc[q] += (double)partials[i * PACC + q];
    }
    const int wave = threadIdx.x >> 6, lane = threadIdx.x & 63;
    #pragma unroll
    for (int q = 0; q < NACC; ++q) {
        double v = acc[q];
        #pragma unroll
        for (int off = 32; off > 0; off >>= 1)
            v += __shfl_down(v, off, 64);
        if (lane == 0) s_red[wave][q] = v;
    }
    __syncthreads();
    if (threadIdx.x == 0) {
        double s[NACC];
        #pragma unroll
        for (int q = 0; q < NACC; ++q) {
            double v = 0.0;
            #pragma unroll
            for (int w = 0; w < TPB / 64; ++w) v += s_red[w][q];
            s[q] = v;
        }
        const double Np = fmax(s[5], 1.0);
        const double PN = fmax(s[6], 1.0);
        out[0] = (float)(s[0] / Np);
        out[1] = (float)(s[1] / Np);
        out[2] = (float)(s[2] / PN);
        out[3] = (float)(s[3] / PN);
        out[4] = (float)(s[4] / Np);
    }
}

extern "C" void kernel_launch(void* const* d_in, const int* in_sizes, int n_in,
                              void* d_out, int out_size, void* d_ws, size_t ws_size,
                              hipStream_t stream) {
    const float* loc     = (const float*)d_in[0];
    const float* conf    = (const float*)d_in[1];
    const float* ploc    = (const float*)d_in[2];
    const float* pconf   = (const float*)d_in[3];
    const float* center  = (const float*)d_in[4];
    const float* priors  = (const float*)d_in[5];
    const float* targets = (const float*)d_in[6];
    char* ws = (char*)d_ws;   // uses 57,344 bytes (partials only)

    dim3 grid(CBX, B_);
    msl_main<<<grid, TPB, 0, stream>>>(loc, conf, ploc, pconf, center, priors,
                                       targets, ws);
    msl_final<<<1, TPB, 0, stream>>>((const float*)ws, (float*)d_out);
}